// Round 7
// baseline (122.470 us; speedup 1.0000x reference)
//
#include <hip/hip_runtime.h>

// SelfAttention: B=4,S=4096,D=256,A=64,O=256, f32 in/out, bf16 MFMA compute.
// R7: k_attn rework: (1) P-redistribution ELIMINATED via t-permuted V staging
// (k = 8*((t>>2)&3) + 4*(t>>4) + (t&3)) so each lane's QK^T outputs are its PV
// B-frag directly (8 cvtpk, no LDS round-trip); (2) fat waves: 8 t-groups x
// 2 s-waves (32 s, 2 K-frags each) -> Q/V LDS reads halved per unit work,
// 16 iters, 1 barrier/iter, double-buffered, load-issue mid-compute.

#define SQN 4096
#define AN 64

typedef short bf16x8 __attribute__((ext_vector_type(8)));
typedef float f32x4 __attribute__((ext_vector_type(4)));

__device__ __forceinline__ unsigned short f2bf(float f) {
    unsigned int u = __float_as_uint(f);
    u += 0x7fffu + ((u >> 16) & 1u);   // RNE
    return (unsigned short)(u >> 16);
}
__device__ __forceinline__ unsigned int cvtpk(float lo, float hi) {
    unsigned int r;
    asm("v_cvt_pk_bf16_f32 %0, %1, %2" : "=v"(r) : "v"(lo), "v"(hi));
    return r;
}
__device__ __forceinline__ float exp2_hw(float x) {
    float r; asm("v_exp_f32 %0, %1" : "=v"(r) : "v"(x)); return r;
}

// ---------------- weight transpose: W[d][a]->WT[(p*64+a)][d] bf16 (Wq scaled), Wo->WoT[o][a]
__global__ __launch_bounds__(256) void k_wtrans(
    const float* __restrict__ Wk, const float* __restrict__ Wq,
    const float* __restrict__ Wv, const float* __restrict__ Wo,
    unsigned short* __restrict__ WT, unsigned short* __restrict__ WoT)
{
    int bidx = blockIdx.x, tid = threadIdx.x;
    if (bidx < 24) {
        int m = bidx >> 3, chunk = bidx & 7;
        const float* src = (m == 0) ? Wk : (m == 1) ? Wq : Wv;
        float scl = (m == 1) ? 0.18033688011112042f : 1.0f;  // 0.125*log2(e)
        unsigned short* dst = WT + (m * 64 + chunk * 8) * 256;
        for (int idx = tid; idx < 8 * 256; idx += 256) {
            int a = chunk * 8 + (idx >> 8), d = idx & 255;
            dst[idx] = f2bf(src[d * 64 + a] * scl);
        }
    } else {
        int chunk = bidx - 24;
        for (int idx = tid; idx < 32 * 64; idx += 256) {
            int o = chunk * 32 + (idx >> 6), a = idx & 63;
            WoT[o * 64 + a] = f2bf(Wo[a * 256 + o]);
        }
    }
}

// ---------------- fused projections: x -> K,Q [s][a] bf16; V -> VT[b*64+a][s]
__global__ __launch_bounds__(256) void k_proj(
    const float* __restrict__ x, const unsigned short* __restrict__ WT,
    unsigned short* __restrict__ Ko, unsigned short* __restrict__ Qo,
    unsigned short* __restrict__ VTo)
{
    __shared__ unsigned short x_lds[32 * 256];
    const int tid = threadIdx.x;
    const int wid = tid >> 6, lane = tid & 63, g = lane >> 4, li = lane & 15;
    const int s0 = blockIdx.x * 32;

    {
        const float4* xs = (const float4*)(x + (size_t)s0 * 256);
        #pragma unroll
        for (int i = 0; i < 8; ++i) {
            int idx4 = i * 256 + tid;
            float4 v = xs[idx4];
            int row = idx4 >> 6, q = idx4 & 63;
            int unit = q >> 1, half = q & 1;
            uint2 u; u.x = cvtpk(v.x, v.y); u.y = cvtpk(v.z, v.w);
            *(uint2*)&x_lds[row * 256 + ((unit ^ (row & 7)) << 3) + half * 4] = u;
        }
    }
    __syncthreads();

    f32x4 acc[3][2] = {};
    #pragma unroll
    for (int dc = 0; dc < 8; ++dc) {
        bf16x8 afr[2];
        #pragma unroll
        for (int sf = 0; sf < 2; ++sf) {
            int ar = sf * 16 + li;
            afr[sf] = *(const bf16x8*)&x_lds[ar * 256 + (((4 * dc + g) ^ (ar & 7)) << 3)];
        }
        #pragma unroll
        for (int c = 0; c < 3; ++c) {
            int wc = (wid * 3 + c) * 16 + li;
            bf16x8 bfr = *(const bf16x8*)&WT[wc * 256 + dc * 32 + 8 * g];
            #pragma unroll
            for (int sf = 0; sf < 2; ++sf)
                acc[c][sf] = __builtin_amdgcn_mfma_f32_16x16x32_bf16(afr[sf], bfr, acc[c][sf], 0, 0, 0);
        }
    }

    const int b = s0 >> 12;
    #pragma unroll
    for (int c = 0; c < 3; ++c) {
        int cfg = wid * 3 + c;
        int p = cfg >> 2, col = (cfg & 3) * 16 + li;
        if (p == 2) {
            #pragma unroll
            for (int sf = 0; sf < 2; ++sf) {
                int sb = (s0 & 4095) + sf * 16 + 4 * g;
                uint2 u;
                u.x = cvtpk(acc[c][sf][0], acc[c][sf][1]);
                u.y = cvtpk(acc[c][sf][2], acc[c][sf][3]);
                *(uint2*)&VTo[(((size_t)(b * 64 + col)) << 12) + sb] = u;
            }
        } else {
            unsigned short* dst = (p == 0) ? Ko : Qo;
            #pragma unroll
            for (int sf = 0; sf < 2; ++sf)
                #pragma unroll
                for (int r = 0; r < 4; ++r)
                    dst[(size_t)(s0 + sf * 16 + 4 * g + r) * 64 + col] = f2bf(acc[c][sf][r]);
        }
    }
}

// ---------------- fused flash attention + split-combine + out-projection
// grid 256 = XCD-swizzled (b, 64-s chunk); block 1024 = 16 waves = 8 t-grp x 2 s-waves.
// grp handles t in [grp*512, +512), 16 tiles of 32. Wave covers 32 s (2 K-frags).
// V staged with k-row permutation k(t) = 8*((t>>2)&3) + 4*(t>>4) + (t&3):
// lane's QK^T outputs (t = 16tf+4g+r) are exactly PV B-frag k-rows 8g..8g+7.
__global__ __launch_bounds__(1024, 4) void k_attn(
    const unsigned short* __restrict__ Qg, const unsigned short* __restrict__ Kg,
    const unsigned short* __restrict__ VTg, const unsigned short* __restrict__ WoT,
    float* __restrict__ out)
{
    __shared__ __attribute__((aligned(16))) char smem[143360];   // 140 KB
    unsigned short* q_lds = (unsigned short*)smem;               // [8 grp][2 buf][32t x 64a] 64 KB
    unsigned short* v_lds = (unsigned short*)(smem + 65536);     // [8 grp][2 buf][64a x 32k] 64 KB
    float* ml            = (float*)(smem + 131072);              // [2][8 h][64 s] 4 KB
    unsigned short* a_lds = (unsigned short*)(smem + 135168);    // [64][64] bf16 swizzled 8 KB
    float* o_part        = (float*)smem;                         // epilogue overlay [8][64][64] f32 128 KB

    const int tid = threadIdx.x;
    const int wid = tid >> 6, lane = tid & 63, g = lane >> 4, li = lane & 15;
    const int grp = wid >> 1, ws = wid & 1;
    // XCD swizzle: each XCD (blockIdx%8) owns one batch-half -> Q/VT L2-resident
    const int xcd = blockIdx.x & 7, idx = blockIdx.x >> 3;
    const int b = xcd >> 1;
    const int s0 = ((xcd & 1) * 32 + idx) * 64;
    const int t_beg = grp * 512;
    const size_t base = (size_t)b * SQN * AN;

    // staging mapping: 128 threads per grp
    const int gt = tid & 127;
    const int qrow = gt >> 2, qseg = gt & 3;          // Q: [32 t][64 a], 2x uint4/thread
    const int vrow = gt >> 1, vhalf = gt & 1;         // V: [64 a][32 t], 2x uint4 -> 4x uint2
    const int qo0 = qrow * 64 + (((2 * qseg)     ^ (qrow & 7)) << 3);
    const int qo1 = qrow * 64 + (((2 * qseg + 1) ^ (qrow & 7)) << 3);
    const int vrot = (vrow >> 1) & 3;
    const int u0 = 2 * vhalf, u1 = 2 * vhalf + 1;
    // k-permuted V offsets: chunk (u, half h) -> ((2u+h+rot)&3)*8 + (u>>1)*4 shorts
    const int vo00 = vrow * 32 + (((2 * u0     + vrot) & 3) << 3) + ((u0 >> 1) << 2);
    const int vo01 = vrow * 32 + (((2 * u0 + 1 + vrot) & 3) << 3) + ((u0 >> 1) << 2);
    const int vo10 = vrow * 32 + (((2 * u1     + vrot) & 3) << 3) + ((u1 >> 1) << 2);
    const int vo11 = vrow * 32 + (((2 * u1 + 1 + vrot) & 3) << 3) + ((u1 >> 1) << 2);
    const unsigned short* qg0 = Qg + base + (size_t)(t_beg + qrow) * 64 + qseg * 16;
    const unsigned short* vg0 = VTg + (((size_t)(b * 64 + vrow)) << 12) + t_beg + vhalf * 16;

    // K fragments: wave covers s = s0 + ws*32 + sf*16 + li
    bf16x8 kf[2][2];
    #pragma unroll
    for (int sf = 0; sf < 2; ++sf) {
        const unsigned short* kp = Kg + base + (size_t)(s0 + ws * 32 + sf * 16 + li) * 64;
        kf[sf][0] = *(const bf16x8*)(kp + 8 * g);
        kf[sf][1] = *(const bf16x8*)(kp + 32 + 8 * g);
    }

    uint4 q0, q1, v0, v1;
    auto issue = [&](int t4) {
        const unsigned short* qp = qg0 + (size_t)t4 * 2048;
        const unsigned short* vp = vg0 + t4 * 32;
        q0 = *(const uint4*)(qp); q1 = *(const uint4*)(qp + 8);
        v0 = *(const uint4*)(vp); v1 = *(const uint4*)(vp + 8);
    };
    auto stage_write = [&](int buf) {
        unsigned short* qb = q_lds + (grp * 2 + buf) * 2048;
        unsigned short* vb = v_lds + (grp * 2 + buf) * 2048;
        *(uint4*)&qb[qo0] = q0;
        *(uint4*)&qb[qo1] = q1;
        uint2 a, b2;
        a.x = v0.x; a.y = v0.y; b2.x = v0.z; b2.y = v0.w;
        *(uint2*)&vb[vo00] = a; *(uint2*)&vb[vo01] = b2;
        a.x = v1.x; a.y = v1.y; b2.x = v1.z; b2.y = v1.w;
        *(uint2*)&vb[vo10] = a; *(uint2*)&vb[vo11] = b2;
    };

    f32x4 ot[4][2] = {};
    float m_run[2] = {-1e30f, -1e30f}, l_run[2] = {0.0f, 0.0f};

    issue(0);
    stage_write(0);
    issue(1);
    __syncthreads();

    for (int i = 0; i < 16; ++i) {
        if (i < 15) stage_write((i + 1) & 1);

        const unsigned short* qb = q_lds + (grp * 2 + (i & 1)) * 2048;
        const unsigned short* vb = v_lds + (grp * 2 + (i & 1)) * 2048;

        // QK^T A-frags
        bf16x8 qa[2][2];
        #pragma unroll
        for (int tf = 0; tf < 2; ++tf) {
            int row = tf * 16 + li;
            qa[tf][0] = *(const bf16x8*)&qb[row * 64 + ((g ^ (row & 7)) << 3)];
            qa[tf][1] = *(const bf16x8*)&qb[row * 64 + (((4 + g) ^ (row & 7)) << 3)];
        }
        if (i < 14) issue(i + 2);          // prefetch under compute

        f32x4 st[2][2] = {};
        #pragma unroll
        for (int tf = 0; tf < 2; ++tf)
            #pragma unroll
            for (int sf = 0; sf < 2; ++sf) {
                st[tf][sf] = __builtin_amdgcn_mfma_f32_16x16x32_bf16(qa[tf][0], kf[sf][0], st[tf][sf], 0, 0, 0);
                st[tf][sf] = __builtin_amdgcn_mfma_f32_16x16x32_bf16(qa[tf][1], kf[sf][1], st[tf][sf], 0, 0, 0);
            }

        // online softmax per sf (lane owns s-col li of each 16-group), defer-max THR=8
        float tm[2];
        #pragma unroll
        for (int sf = 0; sf < 2; ++sf) {
            float a = fmaxf(fmaxf(st[0][sf][0], st[0][sf][1]), fmaxf(st[0][sf][2], st[0][sf][3]));
            float c = fmaxf(fmaxf(st[1][sf][0], st[1][sf][1]), fmaxf(st[1][sf][2], st[1][sf][3]));
            float t = fmaxf(a, c);
            t = fmaxf(t, __shfl_xor(t, 16));
            t = fmaxf(t, __shfl_xor(t, 32));
            tm[sf] = t;
        }
        bool need = (tm[0] > m_run[0] + 8.0f) || (tm[1] > m_run[1] + 8.0f);
        if (__any(need)) {
            #pragma unroll
            for (int sf = 0; sf < 2; ++sf) {
                float m_new = fmaxf(m_run[sf], tm[sf]);
                float alpha = exp2_hw(m_run[sf] - m_new);
                #pragma unroll
                for (int af = 0; af < 4; ++af) {
                    ot[af][sf][0] *= alpha; ot[af][sf][1] *= alpha;
                    ot[af][sf][2] *= alpha; ot[af][sf][3] *= alpha;
                }
                l_run[sf] *= alpha;
                m_run[sf] = m_new;
            }
        }

        // P in-register -> PV B-frags directly (k-permuted V makes this exact)
        union { unsigned int w[4]; bf16x8 v; } pb[2];
        #pragma unroll
        for (int sf = 0; sf < 2; ++sf) {
            float p0 = exp2_hw(st[0][sf][0] - m_run[sf]);
            float p1 = exp2_hw(st[0][sf][1] - m_run[sf]);
            float p2 = exp2_hw(st[0][sf][2] - m_run[sf]);
            float p3 = exp2_hw(st[0][sf][3] - m_run[sf]);
            float p4 = exp2_hw(st[1][sf][0] - m_run[sf]);
            float p5 = exp2_hw(st[1][sf][1] - m_run[sf]);
            float p6 = exp2_hw(st[1][sf][2] - m_run[sf]);
            float p7 = exp2_hw(st[1][sf][3] - m_run[sf]);
            float ts = ((p0 + p1) + (p2 + p3)) + ((p4 + p5) + (p6 + p7));
            pb[sf].w[0] = cvtpk(p0, p1); pb[sf].w[1] = cvtpk(p2, p3);
            pb[sf].w[2] = cvtpk(p4, p5); pb[sf].w[3] = cvtpk(p6, p7);
            ts += __shfl_xor(ts, 16);
            ts += __shfl_xor(ts, 32);
            l_run[sf] += ts;
        }

        // PV: V A-frag shared across both sf
        #pragma unroll
        for (int af = 0; af < 4; ++af) {
            int row = af * 16 + li;
            bf16x8 va = *(const bf16x8*)&vb[row * 32 + (((g + ((row >> 1) & 3)) & 3) << 3)];
            #pragma unroll
            for (int sf = 0; sf < 2; ++sf)
                ot[af][sf] = __builtin_amdgcn_mfma_f32_16x16x32_bf16(va, pb[sf].v, ot[af][sf], 0, 0, 0);
        }

        __syncthreads();
    }

    // ---------------- epilogue: in-LDS 8-split combine + out-projection
    {   // unnormalized partials (a = 16af+4g+r, s = ws*32+sf*16+li), swizzled
        #pragma unroll
        for (int sf = 0; sf < 2; ++sf) {
            int s_loc = ws * 32 + sf * 16 + li;
            float* op = o_part + (size_t)(grp * 64 + s_loc) * 64;
            #pragma unroll
            for (int af = 0; af < 4; ++af) {
                int lu = 4 * af + g;
                float4 o;
                o.x = ot[af][sf][0]; o.y = ot[af][sf][1];
                o.z = ot[af][sf][2]; o.w = ot[af][sf][3];
                *(float4*)(op + ((lu ^ (s_loc & 7)) << 2)) = o;
            }
            if (g == 0) {
                ml[grp * 64 + s_loc] = m_run[sf];
                ml[512 + grp * 64 + s_loc] = l_run[sf];
            }
        }
    }
    __syncthreads();

    {   // combine 8 t-splits -> normalized bf16 attn tile in a_lds
        int row = tid >> 4, ac = (tid & 15) * 4;
        float mm[8], ll[8];
        #pragma unroll
        for (int h = 0; h < 8; ++h) {
            mm[h] = ml[h * 64 + row];
            ll[h] = ml[512 + h * 64 + row];
        }
        float M = mm[0];
        #pragma unroll
        for (int h = 1; h < 8; ++h) M = fmaxf(M, mm[h]);
        float w[8], denom = 0.0f;
        #pragma unroll
        for (int h = 0; h < 8; ++h) { w[h] = exp2_hw(mm[h] - M); denom += w[h] * ll[h]; }
        float inv = 1.0f / denom;
        float4 av = {0.f, 0.f, 0.f, 0.f};
        #pragma unroll
        for (int h = 0; h < 8; ++h) {
            float4 v = *(const float4*)&o_part[(size_t)(h * 64 + row) * 64 + (((ac >> 2) ^ (row & 7)) << 2)];
            av.x += w[h] * v.x; av.y += w[h] * v.y; av.z += w[h] * v.z; av.w += w[h] * v.w;
        }
        int unit = ac >> 3;
        uint2 u; u.x = cvtpk(av.x * inv, av.y * inv); u.y = cvtpk(av.z * inv, av.w * inv);
        *(uint2*)&a_lds[row * 64 + ((unit ^ (row & 7)) << 3) + (ac & 7)] = u;
    }
    __syncthreads();

    {   // out[s][o] = attn @ Wo; wave = (s-quarter sq, o-quarter oq)
        int sq = wid >> 2, oq = wid & 3;
        int row = sq * 16 + li;
        bf16x8 b0 = *(const bf16x8*)&a_lds[row * 64 + ((g ^ (row & 7)) << 3)];
        bf16x8 b1 = *(const bf16x8*)&a_lds[row * 64 + (((4 + g) ^ (row & 7)) << 3)];
        #pragma unroll
        for (int of = 0; of < 4; ++of) {
            const unsigned short* wp = WoT + (size_t)(oq * 64 + of * 16 + li) * 64;
            bf16x8 w0 = *(const bf16x8*)(wp + 8 * g);
            bf16x8 w1 = *(const bf16x8*)(wp + 32 + 8 * g);
            f32x4 acc = {};
            acc = __builtin_amdgcn_mfma_f32_16x16x32_bf16(w0, b0, acc, 0, 0, 0);
            acc = __builtin_amdgcn_mfma_f32_16x16x32_bf16(w1, b1, acc, 0, 0, 0);
            float4 o;
            o.x = acc[0]; o.y = acc[1]; o.z = acc[2]; o.w = acc[3];
            *(float4*)&out[((size_t)b * 4096 + s0 + sq * 16 + li) * 256 + oq * 64 + of * 16 + 4 * g] = o;
        }
    }
}

extern "C" void kernel_launch(void* const* d_in, const int* in_sizes, int n_in,
                              void* d_out, int out_size, void* d_ws, size_t ws_size,
                              hipStream_t stream) {
    const float* x  = (const float*)d_in[0];
    const float* Wk = (const float*)d_in[1];
    const float* Wq = (const float*)d_in[2];
    const float* Wv = (const float*)d_in[3];
    const float* Wo = (const float*)d_in[4];
    float* out = (float*)d_out;

    char* ws = (char*)d_ws;
    unsigned short* WT  = (unsigned short*)(ws);                    // 96 KB  [192][256]
    unsigned short* WoT = (unsigned short*)(ws + 98304);            // 32 KB  [256][64]
    unsigned short* Qb  = (unsigned short*)(ws + 131072);           // 2 MB   [b*4096+s][64]
    unsigned short* Kb  = (unsigned short*)(ws + 131072 + (1u<<21));// 2 MB
    unsigned short* VTb = (unsigned short*)(ws + 131072 + (2u<<21));// 2 MB   [b*64+a][4096]

    k_wtrans<<<32, 256, 0, stream>>>(Wk, Wq, Wv, Wo, WT, WoT);
    k_proj<<<512, 256, 0, stream>>>(x, WT, Kb, Qb, VTb);
    k_attn<<<256, 1024, 0, stream>>>(Qb, Kb, VTb, WoT, out);
}